// Round 9
// baseline (179.126 us; speedup 1.0000x reference)
//
#include <hip/hip_runtime.h>
#include <hip/hip_bf16.h>

#define N_NODES 100000
#define N_EDGES 20000
#define N_PAIRS 640000
#define CH 128      // HEADS * OUT_CH
#define HEADS 4
#define MAXDV 32    // k_vertex fast-path capacity (Poisson(6.4): max ~25)

#define NG_GEMM 1563            // (N_NODES+63)/64
#define NV_RANK 2500            // N_PAIRS/256
#define NE_BLOCKS 125           // ecount blocks
#define ECHUNK 5120             // pairs per ecount block (125*5120 = 640000)
#define NWORDS 10240            // 20480 bins packed 2 per u32
#define SCAN_G 5                // scan groups of 25 blocks

// ---- workspace layout (bytes), all 16B-aligned ----
#define OFF_X0H   0UL           // 12,800,000 bf16 = 25,600,000
#define OFF_XEH   25600000UL    //  2,560,000 bf16 =  5,120,000
#define OFF_LRE   30720000UL    //    640,000 u16  =  1,280,000  (edge local rank)
#define OFF_RKV   32000000UL    //    640,000 u16  =  1,280,000  (vertex rank)
#define OFF_BLK   33280000UL    // 125*10240 u32   =  5,120,000  (per-block packed hist)
#define OFF_GSUM  38400000UL    //   5*10240 u32   =    204,800
#define OFF_WT    38604800UL    //     16,384 bf16 =     32,768
#define OFF_ALPHA 38637568UL    //     80,000 f32  =    320,000
#define OFF_OFFE  38957568UL    //     20,480 i32  =     81,920
#define OFF_ENDE  39039488UL    //     20,480 i32
#define OFF_OFFV  39121408UL    //    100,000 i32  =    400,000
#define OFF_ENDV  39521408UL    //    100,000 i32
#define OFF_PIDXE 39921408UL    //    640,000 i32 (VERTEX ids, edge-grouped)
#define OFF_PIDXV 42481408UL    //    640,000 i32 (EDGE ids, vertex-grouped)
#define OFF_CNTE  45041408UL    //     20,480 i32 (written by scan_p2; no zeroing)
#define OFF_CNTV  45123328UL    //    100,000 i32  } zero region
#define OFF_TOT   45523328UL    //          2 i32  }
#define ZERO_BYTES 400008UL

typedef __attribute__((ext_vector_type(8))) short bf16x8;
typedef __attribute__((ext_vector_type(4))) float f32x4;

__device__ inline short f2bf(float f) {
    __hip_bfloat16 h = __float2bfloat16(f);   // RNE
    return reinterpret_cast<short&>(h);
}
__device__ inline float bf2f(short s) {
    unsigned int u = ((unsigned int)(unsigned short)s) << 16;
    union { unsigned int u; float f; } c; c.u = u;
    return c.f;
}

// ---- W prep: Wt[n][k] = bf16(W[k][n]) ----
__global__ __launch_bounds__(256) void k_wprep(const float* __restrict__ W,
                                               short* __restrict__ Wt) {
    const int idx = blockIdx.x * 256 + threadIdx.x;   // 64 * 256 = 16384
    const int n = idx >> 7, k = idx & 127;
    Wt[n * CH + k] = f2bf(W[k * CH + n]);
}

// ================= FUSED phase 1: ecount ∥ gemm ∥ vrank =================
__device__ inline void gemm_body(int gb, const float* __restrict__ X,
                                 const short* __restrict__ Wt,
                                 short* __restrict__ X0h) {
    const int t = threadIdx.x;
    const int wave = t >> 6, lane = t & 63;
    const int r0 = gb * 64 + (wave >> 1) * 32;
    const int c0 = (wave & 1) * 64;
    const int lrow = lane & 15, lk8 = (lane >> 4) * 8;

    f32x4 acc[2][4] = {};

#pragma unroll
    for (int kk = 0; kk < 4; ++kk) {
        const int ks = kk * 32 + lk8;
        bf16x8 a[2], b[4];
#pragma unroll
        for (int m = 0; m < 2; ++m) {
            int row = r0 + m * 16 + lrow;
            row = min(row, N_NODES - 1);
            const float* p = &X[(size_t)row * CH + ks];
            const float4 x0 = *(const float4*)p;
            const float4 x1 = *(const float4*)(p + 4);
            a[m][0] = f2bf(x0.x); a[m][1] = f2bf(x0.y);
            a[m][2] = f2bf(x0.z); a[m][3] = f2bf(x0.w);
            a[m][4] = f2bf(x1.x); a[m][5] = f2bf(x1.y);
            a[m][6] = f2bf(x1.z); a[m][7] = f2bf(x1.w);
        }
#pragma unroll
        for (int n = 0; n < 4; ++n) {
            int col = c0 + n * 16 + lrow;
            b[n] = *(const bf16x8*)&Wt[col * CH + ks];
        }
#pragma unroll
        for (int m = 0; m < 2; ++m)
#pragma unroll
            for (int n = 0; n < 4; ++n)
                acc[m][n] = __builtin_amdgcn_mfma_f32_16x16x32_bf16(a[m], b[n], acc[m][n], 0, 0, 0);
    }

#pragma unroll
    for (int m = 0; m < 2; ++m) {
#pragma unroll
        for (int reg = 0; reg < 4; ++reg) {
            const int row = r0 + m * 16 + (lane >> 4) * 4 + reg;
            if (row < N_NODES) {
#pragma unroll
                for (int n = 0; n < 4; ++n)
                    X0h[(size_t)row * CH + c0 + n * 16 + (lane & 15)] = f2bf(acc[m][n][reg]);
            }
        }
    }
}

__global__ __launch_bounds__(256) void k_phase1(const float* __restrict__ X,
                                                const short* __restrict__ Wt,
                                                short* __restrict__ X0h,
                                                const int* __restrict__ vertex,
                                                const int* __restrict__ edges,
                                                int* __restrict__ cnt_v,
                                                unsigned short* __restrict__ lrank_e,
                                                unsigned short* __restrict__ rank_v,
                                                unsigned int* __restrict__ blkcnt) {
    __shared__ unsigned int hist[NWORDS];   // 40 KB: 20480 bins packed 2x16b
    const int bid = blockIdx.x;
    const int t = threadIdx.x;

    if (bid < NE_BLOCKS) {
        // ---- ecount: LDS histogram ranking, zero global atomics ----
        for (int i = t; i < NWORDS; i += 256) hist[i] = 0;
        __syncthreads();
        const int base = bid * ECHUNK;
        unsigned short lr[20];
#pragma unroll
        for (int it = 0; it < 20; ++it) {
            const int m = base + it * 256 + t;
            const int e = edges[m];
            const unsigned sh = (unsigned)(e & 1) * 16u;
            unsigned old = atomicAdd(&hist[e >> 1], 1u << sh);
            lr[it] = (unsigned short)((old >> sh) & 0xffffu);
        }
#pragma unroll
        for (int it = 0; it < 20; ++it) lrank_e[base + it * 256 + t] = lr[it];
        __syncthreads();
        for (int w = t; w < NWORDS; w += 256) blkcnt[bid * NWORDS + w] = hist[w];
        return;
    }
    const int r = bid - NE_BLOCKS;
    if (r < 2 * NG_GEMM) {
        if ((r & 1) == 0) { gemm_body(r >> 1, X, Wt, X0h); return; }
        const int m = (r >> 1) * 256 + t;
        rank_v[m] = (unsigned short)atomicAdd(&cnt_v[vertex[m]], 1);
        return;
    }
    const int m = (r - 2 * NG_GEMM + NG_GEMM) * 256 + t;
    rank_v[m] = (unsigned short)atomicAdd(&cnt_v[vertex[m]], 1);
}

// ---- scan p1: group partial sums (25 blocks per group) ----
__global__ __launch_bounds__(256) void k_scan_p1(const unsigned int* __restrict__ blkcnt,
                                                 unsigned int* __restrict__ gsum) {
    const int gid = blockIdx.x * 256 + threadIdx.x;    // 51200
    const int g = gid / NWORDS, w = gid % NWORDS;
    unsigned s = 0;
#pragma unroll 5
    for (int i = 0; i < 25; ++i) s += blkcnt[(g * 25 + i) * NWORDS + w];
    gsum[g * NWORDS + w] = s;
}

// ---- scan p2: 5-way exclusive scan across groups + edge totals ----
__global__ __launch_bounds__(256) void k_scan_p2(unsigned int* __restrict__ gsum,
                                                 int* __restrict__ cnt_e) {
    const int w = blockIdx.x * 256 + threadIdx.x;      // 10240
    unsigned run = 0;
#pragma unroll
    for (int g = 0; g < SCAN_G; ++g) {
        unsigned c = gsum[g * NWORDS + w];
        gsum[g * NWORDS + w] = run;
        run += c;
    }
    cnt_e[2 * w]     = (int)(run & 0xffffu);
    cnt_e[2 * w + 1] = (int)(run >> 16);
}

// ---- scan p3: per-block exclusive prefixes (packed halves) ----
__global__ __launch_bounds__(256) void k_scan_p3(unsigned int* __restrict__ blkcnt,
                                                 const unsigned int* __restrict__ gsum) {
    const int gid = blockIdx.x * 256 + threadIdx.x;    // 51200
    const int g = gid / NWORDS, w = gid % NWORDS;
    unsigned run = gsum[g * NWORDS + w];
#pragma unroll 5
    for (int i = 0; i < 25; ++i) {
        const int idx = (g * 25 + i) * NWORDS + w;
        unsigned c = blkcnt[idx];
        blkcnt[idx] = run;
        run += c;
    }
}

// ------------- offsets (both sides, role by blockIdx) -------------
__global__ __launch_bounds__(256) void k_offsets2(const int* __restrict__ cnt_e,
                                                  int* __restrict__ off_e,
                                                  int* __restrict__ end_e,
                                                  const int* __restrict__ cnt_v,
                                                  int* __restrict__ off_v,
                                                  int* __restrict__ end_v,
                                                  int* __restrict__ totals) {
    __shared__ int s[256];
    __shared__ int base;
    const int bid = blockIdx.x, t = threadIdx.x;
    const int* cnt; int* off; int* end; int* total; int n, i;
    if (bid < 79) { cnt = cnt_e; off = off_e; end = end_e; total = &totals[0]; n = N_EDGES;  i = bid * 256 + t; }
    else          { cnt = cnt_v; off = off_v; end = end_v; total = &totals[1]; n = N_NODES; i = (bid - 79) * 256 + t; }
    const int c = (i < n) ? cnt[i] : 0;
    s[t] = c;
    __syncthreads();
    for (int d = 1; d < 256; d <<= 1) {
        int x = (t >= d) ? s[t - d] : 0;
        __syncthreads();
        s[t] += x;
        __syncthreads();
    }
    if (t == 0) base = atomicAdd(total, s[255]);
    __syncthreads();
    if (i < n) {
        int o = base + s[t] - c;
        off[i] = o;
        end[i] = o + c;
    }
}

// ------- atomic-free scatter -------
__global__ __launch_bounds__(256) void k_scatter(const int* __restrict__ vertex,
                                                 const int* __restrict__ edges,
                                                 const unsigned short* __restrict__ lrank_e,
                                                 const unsigned short* __restrict__ rank_v,
                                                 const unsigned int* __restrict__ blkcnt,
                                                 const int* __restrict__ off_e,
                                                 const int* __restrict__ off_v,
                                                 int* __restrict__ vlist_e,
                                                 int* __restrict__ elist_v) {
    const int m = blockIdx.x * 256 + threadIdx.x;
    const int e = edges[m];
    const int v = vertex[m];
    const int b = m / ECHUNK;
    const unsigned pw = blkcnt[b * NWORDS + (e >> 1)];
    const int er = (int)((pw >> ((unsigned)(e & 1) * 16u)) & 0xffffu) + (int)lrank_e[m];
    vlist_e[off_e[e] + er] = v;
    elist_v[off_v[v] + (int)rank_v[m]] = e;
}

// --------- per-edge: 32 lanes x 4ch; bf16 gathers, f32 accumulate ---------
__global__ __launch_bounds__(256) void k_edge(const short* __restrict__ X0h,
                                              const int* __restrict__ off_e,
                                              const int* __restrict__ end_e,
                                              const int* __restrict__ vlist,
                                              const float* __restrict__ att,
                                              short* __restrict__ Xeh,
                                              float* __restrict__ alpha_le) {
    const int t = threadIdx.x;
    const int slot = t >> 5, lane = t & 31, h = lane >> 3;
    const int e = blockIdx.x * 8 + slot;
    const int s = off_e[e], en = end_e[e];
    const int deg = en - s;

    float4 acc = make_float4(0.f, 0.f, 0.f, 0.f);
    for (int c0 = 0; c0 < deg; c0 += 32) {
        const int cn = min(32, deg - c0);
        int vl = (lane < cn) ? vlist[s + c0 + lane] : 0;
#pragma unroll 4
        for (int j = 0; j < cn; ++j) {
            int vj = __shfl(vl, j, 32);
            short4 x = *(const short4*)&X0h[(size_t)vj * CH + (lane << 2)];
            acc.x += bf2f(x.x); acc.y += bf2f(x.y);
            acc.z += bf2f(x.z); acc.w += bf2f(x.w);
        }
    }
    const float invd = 1.0f / fmaxf((float)deg, 1.0f);
    float4 xe = make_float4(acc.x * invd, acc.y * invd, acc.z * invd, acc.w * invd);
    short4 xh;
    xh.x = f2bf(xe.x); xh.y = f2bf(xe.y); xh.z = f2bf(xe.z); xh.w = f2bf(xe.w);
    *(short4*)&Xeh[(size_t)e * CH + (lane << 2)] = xh;

    const float4 av = *(const float4*)&att[lane << 2];
    float p = xe.x * av.x + xe.y * av.y + xe.z * av.z + xe.w * av.w;
#pragma unroll
    for (int o = 4; o; o >>= 1) p += __shfl_xor(p, o);
    if ((lane & 7) == 0) {
        float a = p;
        alpha_le[e * HEADS + h] = (a > 0.f) ? a : 0.01f * a;
    }
}

// --------- per-vertex: bf16 gathers; softmax + weighted sum + residual ---------
__global__ __launch_bounds__(256) void k_vertex(const short* __restrict__ X0h,
                                                const short* __restrict__ Xeh,
                                                const float* __restrict__ alpha_le,
                                                const int* __restrict__ off_v,
                                                const int* __restrict__ end_v,
                                                const int* __restrict__ elist,
                                                float* __restrict__ out) {
    const int t = threadIdx.x;
    const int slot = t >> 5, lane = t & 31, h = lane >> 3;
    const int v = blockIdx.x * 8 + slot;
    const int s = off_v[v], en = end_v[v];
    const int deg = en - s;

    __shared__ int   se[8][MAXDV];
    __shared__ float sa[8][MAXDV * HEADS];

    if (deg <= MAXDV && lane < deg) {
        int e = elist[s + lane];
        se[slot][lane] = e;
        *(float4*)&sa[slot][lane << 2] = *(const float4*)&alpha_le[e * HEADS];
    }
    const short4 resh = *(const short4*)&X0h[(size_t)v * CH + (lane << 2)];
    __syncthreads();

    float4 acc = make_float4(0.f, 0.f, 0.f, 0.f);
    if (deg <= MAXDV) {
        float mx = -INFINITY;
        for (int j = 0; j < deg; ++j) mx = fmaxf(mx, sa[slot][(j << 2) + h]);
        float ssum = 0.f;
        for (int j = 0; j < deg; ++j) ssum += __expf(sa[slot][(j << 2) + h] - mx);
        const float inv = 1.0f / (ssum + 1e-8f);
        for (int j = 0; j < deg; ++j) {
            float w = __expf(sa[slot][(j << 2) + h] - mx) * inv;
            short4 x = *(const short4*)&Xeh[(size_t)se[slot][j] * CH + (lane << 2)];
            acc.x += w * bf2f(x.x); acc.y += w * bf2f(x.y);
            acc.z += w * bf2f(x.z); acc.w += w * bf2f(x.w);
        }
    } else {
        float mx = -INFINITY;
        for (int j = 0; j < deg; ++j) mx = fmaxf(mx, alpha_le[elist[s + j] * HEADS + h]);
        float ssum = 0.f;
        for (int j = 0; j < deg; ++j) ssum += __expf(alpha_le[elist[s + j] * HEADS + h] - mx);
        const float inv = 1.0f / (ssum + 1e-8f);
        for (int j = 0; j < deg; ++j) {
            int e = elist[s + j];
            float w = __expf(alpha_le[e * HEADS + h] - mx) * inv;
            short4 x = *(const short4*)&Xeh[(size_t)e * CH + (lane << 2)];
            acc.x += w * bf2f(x.x); acc.y += w * bf2f(x.y);
            acc.z += w * bf2f(x.z); acc.w += w * bf2f(x.w);
        }
    }
    float4 o = make_float4(acc.x + bf2f(resh.x), acc.y + bf2f(resh.y),
                           acc.z + bf2f(resh.z), acc.w + bf2f(resh.w));
    ((float4*)out)[(size_t)v * 32 + lane] = o;
}

extern "C" void kernel_launch(void* const* d_in, const int* in_sizes, int n_in,
                              void* d_out, int out_size, void* d_ws, size_t ws_size,
                              hipStream_t stream) {
    const float* X      = (const float*)d_in[0];
    const float* W      = (const float*)d_in[1];
    const float* att    = (const float*)d_in[2];
    const int*   vertex = (const int*)d_in[3];
    const int*   edges  = (const int*)d_in[4];
    float* out = (float*)d_out;

    char* ws = (char*)d_ws;
    short* X0h      = (short*)(ws + OFF_X0H);
    short* Xeh      = (short*)(ws + OFF_XEH);
    unsigned short* lrank_e = (unsigned short*)(ws + OFF_LRE);
    unsigned short* rank_v  = (unsigned short*)(ws + OFF_RKV);
    unsigned int*   blkcnt  = (unsigned int*)(ws + OFF_BLK);
    unsigned int*   gsum    = (unsigned int*)(ws + OFF_GSUM);
    short* Wt       = (short*)(ws + OFF_WT);
    float* alpha_le = (float*)(ws + OFF_ALPHA);
    int* off_e   = (int*)(ws + OFF_OFFE);
    int* end_e   = (int*)(ws + OFF_ENDE);
    int* off_v   = (int*)(ws + OFF_OFFV);
    int* end_v   = (int*)(ws + OFF_ENDV);
    int* vlist_e = (int*)(ws + OFF_PIDXE);
    int* elist_v = (int*)(ws + OFF_PIDXV);
    int* cnt_e   = (int*)(ws + OFF_CNTE);
    int* cnt_v   = (int*)(ws + OFF_CNTV);
    int* totals  = (int*)(ws + OFF_TOT);

    hipMemsetAsync(ws + OFF_CNTV, 0, ZERO_BYTES, stream);

    k_wprep<<<64, 256, 0, stream>>>(W, Wt);
    k_phase1<<<NE_BLOCKS + 2 * NG_GEMM + (NV_RANK - NG_GEMM), 256, 0, stream>>>(
        X, Wt, X0h, vertex, edges, cnt_v, lrank_e, rank_v, blkcnt);
    k_scan_p1<<<200, 256, 0, stream>>>(blkcnt, gsum);
    k_scan_p2<<<40, 256, 0, stream>>>(gsum, cnt_e);
    k_scan_p3<<<200, 256, 0, stream>>>(blkcnt, gsum);
    k_offsets2<<<79 + 391, 256, 0, stream>>>(cnt_e, off_e, end_e, cnt_v, off_v, end_v, totals);
    k_scatter<<<N_PAIRS / 256, 256, 0, stream>>>(vertex, edges, lrank_e, rank_v, blkcnt,
                                                 off_e, off_v, vlist_e, elist_v);
    k_edge<<<N_EDGES / 8, 256, 0, stream>>>(X0h, off_e, end_e, vlist_e, att, Xeh, alpha_le);
    k_vertex<<<N_NODES / 8, 256, 0, stream>>>(X0h, Xeh, alpha_le, off_v, end_v, elist_v, out);
}

// Round 10
// 166.483 us; speedup vs baseline: 1.0759x; 1.0759x over previous
//
#include <hip/hip_runtime.h>
#include <hip/hip_bf16.h>

#define N_NODES 100000
#define N_EDGES 20000
#define N_PAIRS 640000
#define CH 128      // HEADS * OUT_CH
#define HEADS 4
#define MAXDV 32    // k_vertex fast-path capacity (Poisson(6.4): max ~25)

#define NG_GEMM 1563            // (N_NODES+63)/64
#define NCHUNK 125              // pair chunks
#define ECHUNK 5120             // pairs per chunk
#define EW 5120                 // edge hist words (20480 bins @ 4x8b)
#define VWR 6250                // vertex hist words per range (25000 bins @ 4x8b)
#define NRANGE 4
#define VBIN_R 25000

// ---- workspace layout (bytes), all 16B-aligned ----
#define OFF_X0H   0UL           // 25,600,000
#define OFF_XEH   25600000UL    //  5,120,000
#define OFF_LRE   30720000UL    //    640,000 u8 (edge local rank)
#define OFF_LRV   31360000UL    //    640,000 u8 (vertex local rank)
#define OFF_BLKE  32000000UL    // 125*5120 u32  =  2,560,000
#define OFF_BLKV  34560000UL    // 500*6250 u32  = 12,500,000
#define OFF_GSE   47060000UL    //   5*5120 u32  =    102,400
#define OFF_GSV   47162400UL    //  20*6250 u32  =    500,000
#define OFF_WT    47662400UL    //     32,768
#define OFF_ALPHA 47695168UL    //    320,000
#define OFF_OFFE  48015168UL    //     81,920 (20480 i32)
#define OFF_ENDE  48097088UL    //     81,920
#define OFF_OFFV  48179008UL    //    400,000
#define OFF_ENDV  48579008UL    //    400,000
#define OFF_PIDXE 48979008UL    //  2,560,000 (VERTEX ids, edge-grouped)
#define OFF_PIDXV 51539008UL    //  2,560,000 (EDGE ids, vertex-grouped)
#define OFF_CNTE  54099008UL    //     81,920 (written by scan_p2)
#define OFF_CNTV  54180928UL    //    400,000 (written by scan_p2)
#define OFF_TOT   54580928UL    //          8  } only zero region
#define ZERO_BYTES 8UL

typedef __attribute__((ext_vector_type(8))) short bf16x8;
typedef __attribute__((ext_vector_type(4))) float f32x4;

__device__ inline short f2bf(float f) {
    __hip_bfloat16 h = __float2bfloat16(f);   // RNE
    return reinterpret_cast<short&>(h);
}
__device__ inline float bf2f(short s) {
    unsigned int u = ((unsigned int)(unsigned short)s) << 16;
    union { unsigned int u; float f; } c; c.u = u;
    return c.f;
}

// ---- W prep: Wt[n][k] = bf16(W[k][n]) ----
__global__ __launch_bounds__(256) void k_wprep(const float* __restrict__ W,
                                               short* __restrict__ Wt) {
    const int idx = blockIdx.x * 256 + threadIdx.x;   // 64 * 256
    const int n = idx >> 7, k = idx & 127;
    Wt[n * CH + k] = f2bf(W[k * CH + n]);
}

__device__ inline void gemm_body(int gb, const float* __restrict__ X,
                                 const short* __restrict__ Wt,
                                 short* __restrict__ X0h) {
    const int t = threadIdx.x;
    const int wave = t >> 6, lane = t & 63;
    const int r0 = gb * 64 + (wave >> 1) * 32;
    const int c0 = (wave & 1) * 64;
    const int lrow = lane & 15, lk8 = (lane >> 4) * 8;

    f32x4 acc[2][4] = {};

#pragma unroll
    for (int kk = 0; kk < 4; ++kk) {
        const int ks = kk * 32 + lk8;
        bf16x8 a[2], b[4];
#pragma unroll
        for (int m = 0; m < 2; ++m) {
            int row = r0 + m * 16 + lrow;
            row = min(row, N_NODES - 1);
            const float* p = &X[(size_t)row * CH + ks];
            const float4 x0 = *(const float4*)p;
            const float4 x1 = *(const float4*)(p + 4);
            a[m][0] = f2bf(x0.x); a[m][1] = f2bf(x0.y);
            a[m][2] = f2bf(x0.z); a[m][3] = f2bf(x0.w);
            a[m][4] = f2bf(x1.x); a[m][5] = f2bf(x1.y);
            a[m][6] = f2bf(x1.z); a[m][7] = f2bf(x1.w);
        }
#pragma unroll
        for (int n = 0; n < 4; ++n) {
            int col = c0 + n * 16 + lrow;
            b[n] = *(const bf16x8*)&Wt[col * CH + ks];
        }
#pragma unroll
        for (int m = 0; m < 2; ++m)
#pragma unroll
            for (int n = 0; n < 4; ++n)
                acc[m][n] = __builtin_amdgcn_mfma_f32_16x16x32_bf16(a[m], b[n], acc[m][n], 0, 0, 0);
    }

#pragma unroll
    for (int m = 0; m < 2; ++m) {
#pragma unroll
        for (int reg = 0; reg < 4; ++reg) {
            const int row = r0 + m * 16 + (lane >> 4) * 4 + reg;
            if (row < N_NODES) {
#pragma unroll
                for (int n = 0; n < 4; ++n)
                    X0h[(size_t)row * CH + c0 + n * 16 + (lane & 15)] = f2bf(acc[m][n][reg]);
            }
        }
    }
}

// ============ FUSED phase 1: vcount(500) | ecount(125) | gemm(1563) ============
// Zero global returning atomics: all ranking via per-block LDS histograms
// (8-bit packed, 4 bins/word; per-block per-bin <= total degree < 256).
__global__ __launch_bounds__(256) void k_phase1(const float* __restrict__ X,
                                                const short* __restrict__ Wt,
                                                short* __restrict__ X0h,
                                                const int* __restrict__ vertex,
                                                const int* __restrict__ edges,
                                                unsigned char* __restrict__ lrank_e,
                                                unsigned char* __restrict__ lrank_v,
                                                unsigned int* __restrict__ blkcnt_e,
                                                unsigned int* __restrict__ blkcnt_v) {
    __shared__ unsigned int hist[VWR];   // 25 KB
    const int bid = blockIdx.x;
    const int t = threadIdx.x;

    if (bid < NRANGE * NCHUNK) {
        // ---- vcount: range r, chunk c ----
        const int r = bid & 3, c = bid >> 2;
        for (int i = t; i < VWR; i += 256) hist[i] = 0;
        __syncthreads();
        const int base = c * ECHUNK;
        const int vmin = r * VBIN_R;
#pragma unroll
        for (int it = 0; it < 20; ++it) {
            const int m = base + it * 256 + t;
            const int loc = vertex[m] - vmin;
            if ((unsigned)loc < (unsigned)VBIN_R) {
                const unsigned sh = (unsigned)(loc & 3) * 8u;
                unsigned old = atomicAdd(&hist[loc >> 2], 1u << sh);
                lrank_v[m] = (unsigned char)((old >> sh) & 0xffu);
            }
        }
        __syncthreads();
        unsigned int* dst = &blkcnt_v[(size_t)(r * NCHUNK + c) * VWR];
        for (int w = t; w < VWR; w += 256) dst[w] = hist[w];
        return;
    }
    if (bid < NRANGE * NCHUNK + NCHUNK) {
        // ---- ecount: chunk c ----
        const int c = bid - NRANGE * NCHUNK;
        for (int i = t; i < EW; i += 256) hist[i] = 0;
        __syncthreads();
        const int base = c * ECHUNK;
#pragma unroll
        for (int it = 0; it < 20; ++it) {
            const int m = base + it * 256 + t;
            const int e = edges[m];
            const unsigned sh = (unsigned)(e & 3) * 8u;
            unsigned old = atomicAdd(&hist[e >> 2], 1u << sh);
            lrank_e[m] = (unsigned char)((old >> sh) & 0xffu);
        }
        __syncthreads();
        unsigned int* dst = &blkcnt_e[(size_t)c * EW];
        for (int w = t; w < EW; w += 256) dst[w] = hist[w];
        return;
    }
    gemm_body(bid - (NRANGE * NCHUNK + NCHUNK), X, Wt, X0h);
}

// ---- scan p1: group partial sums (25 chunks/group); packed adds (no carry) ----
__global__ __launch_bounds__(256) void k_scan_p1(const unsigned int* __restrict__ blkcnt_e,
                                                 const unsigned int* __restrict__ blkcnt_v,
                                                 unsigned int* __restrict__ gse,
                                                 unsigned int* __restrict__ gsv) {
    const int bid = blockIdx.x;
    if (bid < 100) {                                  // edge: 5 groups x 5120
        const int gid = bid * 256 + threadIdx.x;
        const int g = gid / EW, w = gid % EW;
        unsigned s = 0;
#pragma unroll 5
        for (int i = 0; i < 25; ++i) s += blkcnt_e[(size_t)(g * 25 + i) * EW + w];
        gse[g * EW + w] = s;
        return;
    }
    const int vid = (bid - 100) * 256 + threadIdx.x;  // vertex: 20 groups x 6250
    if (vid >= 20 * VWR) return;
    const int g = vid / VWR, w = vid % VWR;
    const int r = g / 5, cg = g % 5;
    unsigned s = 0;
#pragma unroll 5
    for (int i = 0; i < 25; ++i)
        s += blkcnt_v[(size_t)(r * NCHUNK + cg * 25 + i) * VWR + w];
    gsv[g * VWR + w] = s;
}

// ---- scan p2: exclusive scan across groups + expand totals to cnt arrays ----
__global__ __launch_bounds__(256) void k_scan_p2(unsigned int* __restrict__ gse,
                                                 unsigned int* __restrict__ gsv,
                                                 int* __restrict__ cnt_e,
                                                 int* __restrict__ cnt_v) {
    const int bid = blockIdx.x;
    if (bid < 20) {                                   // edge: 5120 words
        const int w = bid * 256 + threadIdx.x;
        unsigned run = 0;
#pragma unroll
        for (int g = 0; g < 5; ++g) {
            unsigned c = gse[g * EW + w];
            gse[g * EW + w] = run;
            run += c;
        }
        int4 o = { (int)(run & 0xffu), (int)((run >> 8) & 0xffu),
                   (int)((run >> 16) & 0xffu), (int)(run >> 24) };
        *(int4*)&cnt_e[4 * w] = o;
        return;
    }
    const int id = (bid - 20) * 256 + threadIdx.x;    // vertex: 4 ranges x 6250
    if (id >= NRANGE * VWR) return;
    const int r = id / VWR, w = id % VWR;
    unsigned run = 0;
#pragma unroll
    for (int g = r * 5; g < r * 5 + 5; ++g) {
        unsigned c = gsv[g * VWR + w];
        gsv[g * VWR + w] = run;
        run += c;
    }
    int4 o = { (int)(run & 0xffu), (int)((run >> 8) & 0xffu),
               (int)((run >> 16) & 0xffu), (int)(run >> 24) };
    *(int4*)&cnt_v[r * VBIN_R + 4 * w] = o;
}

// ---- scan p3: per-chunk exclusive prefixes (packed adds) ----
__global__ __launch_bounds__(256) void k_scan_p3(unsigned int* __restrict__ blkcnt_e,
                                                 unsigned int* __restrict__ blkcnt_v,
                                                 const unsigned int* __restrict__ gse,
                                                 const unsigned int* __restrict__ gsv) {
    const int bid = blockIdx.x;
    if (bid < 100) {
        const int gid = bid * 256 + threadIdx.x;
        const int g = gid / EW, w = gid % EW;
        unsigned run = gse[g * EW + w];
#pragma unroll 5
        for (int i = 0; i < 25; ++i) {
            const size_t idx = (size_t)(g * 25 + i) * EW + w;
            unsigned c = blkcnt_e[idx];
            blkcnt_e[idx] = run;
            run += c;
        }
        return;
    }
    const int vid = (bid - 100) * 256 + threadIdx.x;
    if (vid >= 20 * VWR) return;
    const int g = vid / VWR, w = vid % VWR;
    const int r = g / 5, cg = g % 5;
    unsigned run = gsv[g * VWR + w];
#pragma unroll 5
    for (int i = 0; i < 25; ++i) {
        const size_t idx = (size_t)(r * NCHUNK + cg * 25 + i) * VWR + w;
        unsigned c = blkcnt_v[idx];
        blkcnt_v[idx] = run;
        run += c;
    }
}

// ------------- offsets (both sides, role by blockIdx) -------------
__global__ __launch_bounds__(256) void k_offsets2(const int* __restrict__ cnt_e,
                                                  int* __restrict__ off_e,
                                                  int* __restrict__ end_e,
                                                  const int* __restrict__ cnt_v,
                                                  int* __restrict__ off_v,
                                                  int* __restrict__ end_v,
                                                  int* __restrict__ totals) {
    __shared__ int s[256];
    __shared__ int base;
    const int bid = blockIdx.x, t = threadIdx.x;
    const int* cnt; int* off; int* end; int* total; int n, i;
    if (bid < 79) { cnt = cnt_e; off = off_e; end = end_e; total = &totals[0]; n = N_EDGES;  i = bid * 256 + t; }
    else          { cnt = cnt_v; off = off_v; end = end_v; total = &totals[1]; n = N_NODES; i = (bid - 79) * 256 + t; }
    const int c = (i < n) ? cnt[i] : 0;
    s[t] = c;
    __syncthreads();
    for (int d = 1; d < 256; d <<= 1) {
        int x = (t >= d) ? s[t - d] : 0;
        __syncthreads();
        s[t] += x;
        __syncthreads();
    }
    if (t == 0) base = atomicAdd(total, s[255]);
    __syncthreads();
    if (i < n) {
        int o = base + s[t] - c;
        off[i] = o;
        end[i] = o + c;
    }
}

// ------- atomic-free scatter: slot = off[bin] + chunkPrefix + localRank -------
__global__ __launch_bounds__(256) void k_scatter(const int* __restrict__ vertex,
                                                 const int* __restrict__ edges,
                                                 const unsigned char* __restrict__ lrank_e,
                                                 const unsigned char* __restrict__ lrank_v,
                                                 const unsigned int* __restrict__ blkcnt_e,
                                                 const unsigned int* __restrict__ blkcnt_v,
                                                 const int* __restrict__ off_e,
                                                 const int* __restrict__ off_v,
                                                 int* __restrict__ vlist_e,
                                                 int* __restrict__ elist_v) {
    const int m = blockIdx.x * 256 + threadIdx.x;
    const int e = edges[m];
    const int v = vertex[m];
    const int c = m / ECHUNK;
    const unsigned pe = blkcnt_e[(size_t)c * EW + (e >> 2)];
    const int er = (int)((pe >> ((unsigned)(e & 3) * 8u)) & 0xffu) + (int)lrank_e[m];
    const int r = v / VBIN_R, loc = v - r * VBIN_R;
    const unsigned pv = blkcnt_v[(size_t)(r * NCHUNK + c) * VWR + (loc >> 2)];
    const int vr = (int)((pv >> ((unsigned)(loc & 3) * 8u)) & 0xffu) + (int)lrank_v[m];
    vlist_e[off_e[e] + er] = v;
    elist_v[off_v[v] + vr] = e;
}

// --------- per-edge: 32 lanes x 4ch; bf16 gathers, f32 accumulate ---------
__global__ __launch_bounds__(256) void k_edge(const short* __restrict__ X0h,
                                              const int* __restrict__ off_e,
                                              const int* __restrict__ end_e,
                                              const int* __restrict__ vlist,
                                              const float* __restrict__ att,
                                              short* __restrict__ Xeh,
                                              float* __restrict__ alpha_le) {
    const int t = threadIdx.x;
    const int slot = t >> 5, lane = t & 31, h = lane >> 3;
    const int e = blockIdx.x * 8 + slot;
    const int s = off_e[e], en = end_e[e];
    const int deg = en - s;

    float4 acc = make_float4(0.f, 0.f, 0.f, 0.f);
    for (int c0 = 0; c0 < deg; c0 += 32) {
        const int cn = min(32, deg - c0);
        int vl = (lane < cn) ? vlist[s + c0 + lane] : 0;
#pragma unroll 4
        for (int j = 0; j < cn; ++j) {
            int vj = __shfl(vl, j, 32);
            short4 x = *(const short4*)&X0h[(size_t)vj * CH + (lane << 2)];
            acc.x += bf2f(x.x); acc.y += bf2f(x.y);
            acc.z += bf2f(x.z); acc.w += bf2f(x.w);
        }
    }
    const float invd = 1.0f / fmaxf((float)deg, 1.0f);
    float4 xe = make_float4(acc.x * invd, acc.y * invd, acc.z * invd, acc.w * invd);
    short4 xh;
    xh.x = f2bf(xe.x); xh.y = f2bf(xe.y); xh.z = f2bf(xe.z); xh.w = f2bf(xe.w);
    *(short4*)&Xeh[(size_t)e * CH + (lane << 2)] = xh;

    const float4 av = *(const float4*)&att[lane << 2];
    float p = xe.x * av.x + xe.y * av.y + xe.z * av.z + xe.w * av.w;
#pragma unroll
    for (int o = 4; o; o >>= 1) p += __shfl_xor(p, o);
    if ((lane & 7) == 0) {
        float a = p;
        alpha_le[e * HEADS + h] = (a > 0.f) ? a : 0.01f * a;
    }
}

// --------- per-vertex: bf16 gathers; softmax + weighted sum + residual ---------
__global__ __launch_bounds__(256) void k_vertex(const short* __restrict__ X0h,
                                                const short* __restrict__ Xeh,
                                                const float* __restrict__ alpha_le,
                                                const int* __restrict__ off_v,
                                                const int* __restrict__ end_v,
                                                const int* __restrict__ elist,
                                                float* __restrict__ out) {
    const int t = threadIdx.x;
    const int slot = t >> 5, lane = t & 31, h = lane >> 3;
    const int v = blockIdx.x * 8 + slot;
    const int s = off_v[v], en = end_v[v];
    const int deg = en - s;

    __shared__ int   se[8][MAXDV];
    __shared__ float sa[8][MAXDV * HEADS];

    if (deg <= MAXDV && lane < deg) {
        int e = elist[s + lane];
        se[slot][lane] = e;
        *(float4*)&sa[slot][lane << 2] = *(const float4*)&alpha_le[e * HEADS];
    }
    const short4 resh = *(const short4*)&X0h[(size_t)v * CH + (lane << 2)];
    __syncthreads();

    float4 acc = make_float4(0.f, 0.f, 0.f, 0.f);
    if (deg <= MAXDV) {
        float mx = -INFINITY;
        for (int j = 0; j < deg; ++j) mx = fmaxf(mx, sa[slot][(j << 2) + h]);
        float ssum = 0.f;
        for (int j = 0; j < deg; ++j) ssum += __expf(sa[slot][(j << 2) + h] - mx);
        const float inv = 1.0f / (ssum + 1e-8f);
        for (int j = 0; j < deg; ++j) {
            float w = __expf(sa[slot][(j << 2) + h] - mx) * inv;
            short4 x = *(const short4*)&Xeh[(size_t)se[slot][j] * CH + (lane << 2)];
            acc.x += w * bf2f(x.x); acc.y += w * bf2f(x.y);
            acc.z += w * bf2f(x.z); acc.w += w * bf2f(x.w);
        }
    } else {
        float mx = -INFINITY;
        for (int j = 0; j < deg; ++j) mx = fmaxf(mx, alpha_le[elist[s + j] * HEADS + h]);
        float ssum = 0.f;
        for (int j = 0; j < deg; ++j) ssum += __expf(alpha_le[elist[s + j] * HEADS + h] - mx);
        const float inv = 1.0f / (ssum + 1e-8f);
        for (int j = 0; j < deg; ++j) {
            int e = elist[s + j];
            float w = __expf(alpha_le[e * HEADS + h] - mx) * inv;
            short4 x = *(const short4*)&Xeh[(size_t)e * CH + (lane << 2)];
            acc.x += w * bf2f(x.x); acc.y += w * bf2f(x.y);
            acc.z += w * bf2f(x.z); acc.w += w * bf2f(x.w);
        }
    }
    float4 o = make_float4(acc.x + bf2f(resh.x), acc.y + bf2f(resh.y),
                           acc.z + bf2f(resh.z), acc.w + bf2f(resh.w));
    ((float4*)out)[(size_t)v * 32 + lane] = o;
}

extern "C" void kernel_launch(void* const* d_in, const int* in_sizes, int n_in,
                              void* d_out, int out_size, void* d_ws, size_t ws_size,
                              hipStream_t stream) {
    const float* X      = (const float*)d_in[0];
    const float* W      = (const float*)d_in[1];
    const float* att    = (const float*)d_in[2];
    const int*   vertex = (const int*)d_in[3];
    const int*   edges  = (const int*)d_in[4];
    float* out = (float*)d_out;

    char* ws = (char*)d_ws;
    short* X0h      = (short*)(ws + OFF_X0H);
    short* Xeh      = (short*)(ws + OFF_XEH);
    unsigned char* lrank_e = (unsigned char*)(ws + OFF_LRE);
    unsigned char* lrank_v = (unsigned char*)(ws + OFF_LRV);
    unsigned int*  blkcnt_e = (unsigned int*)(ws + OFF_BLKE);
    unsigned int*  blkcnt_v = (unsigned int*)(ws + OFF_BLKV);
    unsigned int*  gse      = (unsigned int*)(ws + OFF_GSE);
    unsigned int*  gsv      = (unsigned int*)(ws + OFF_GSV);
    short* Wt       = (short*)(ws + OFF_WT);
    float* alpha_le = (float*)(ws + OFF_ALPHA);
    int* off_e   = (int*)(ws + OFF_OFFE);
    int* end_e   = (int*)(ws + OFF_ENDE);
    int* off_v   = (int*)(ws + OFF_OFFV);
    int* end_v   = (int*)(ws + OFF_ENDV);
    int* vlist_e = (int*)(ws + OFF_PIDXE);
    int* elist_v = (int*)(ws + OFF_PIDXV);
    int* cnt_e   = (int*)(ws + OFF_CNTE);
    int* cnt_v   = (int*)(ws + OFF_CNTV);
    int* totals  = (int*)(ws + OFF_TOT);

    hipMemsetAsync(ws + OFF_TOT, 0, ZERO_BYTES, stream);

    k_wprep<<<64, 256, 0, stream>>>(W, Wt);
    k_phase1<<<NRANGE * NCHUNK + NCHUNK + NG_GEMM, 256, 0, stream>>>(
        X, Wt, X0h, vertex, edges, lrank_e, lrank_v, blkcnt_e, blkcnt_v);
    k_scan_p1<<<100 + 489, 256, 0, stream>>>(blkcnt_e, blkcnt_v, gse, gsv);
    k_scan_p2<<<20 + 98, 256, 0, stream>>>(gse, gsv, cnt_e, cnt_v);
    k_scan_p3<<<100 + 489, 256, 0, stream>>>(blkcnt_e, blkcnt_v, gse, gsv);
    k_offsets2<<<79 + 391, 256, 0, stream>>>(cnt_e, off_e, end_e, cnt_v, off_v, end_v, totals);
    k_scatter<<<N_PAIRS / 256, 256, 0, stream>>>(vertex, edges, lrank_e, lrank_v,
                                                 blkcnt_e, blkcnt_v, off_e, off_v,
                                                 vlist_e, elist_v);
    k_edge<<<N_EDGES / 8, 256, 0, stream>>>(X0h, off_e, end_e, vlist_e, att, Xeh, alpha_le);
    k_vertex<<<N_NODES / 8, 256, 0, stream>>>(X0h, Xeh, alpha_le, off_v, end_v, elist_v, out);
}

// Round 11
// 160.553 us; speedup vs baseline: 1.1157x; 1.0369x over previous
//
#include <hip/hip_runtime.h>
#include <hip/hip_bf16.h>

#define N_NODES 100000
#define N_EDGES 20000
#define N_PAIRS 640000
#define CH 128      // HEADS * OUT_CH
#define HEADS 4
#define MAXDV 32    // k_vertex fast-path capacity (Poisson(6.4): max ~25)

#define NG_GEMM 1563            // (N_NODES+63)/64
#define NCHUNK 125              // pair chunks
#define ECHUNK 5120             // pairs per chunk
#define EW 5120                 // edge hist words (20480 bins @ 4x8b)
#define VWR 6250                // vertex hist words per range (25000 bins @ 4x8b)
#define NRANGE 4
#define VBIN_R 25000

// ---- workspace layout (bytes), all 16B-aligned ----
#define OFF_X0H   0UL           // 25,600,000
#define OFF_XEH   25600000UL    //  5,120,000
#define OFF_LRE   30720000UL    //    640,000 u8 (edge local rank)
#define OFF_LRV   31360000UL    //    640,000 u8 (vertex local rank)
#define OFF_BLKE  32000000UL    // 125*5120 u32  =  2,560,000
#define OFF_BLKV  34560000UL    // 500*6250 u32  = 12,500,000
#define OFF_GSE   47060000UL    //   5*5120 u32  =    102,400
#define OFF_GSV   47162400UL    //  20*6250 u32  =    500,000
#define OFF_WT    47662400UL    //     32,768
#define OFF_ALPHA 47695168UL    //    320,000
#define OFF_OFFE  48015168UL    //     81,920 (20480 i32)
#define OFF_ENDE  48097088UL    //     81,920
#define OFF_OFFV  48179008UL    //    400,000
#define OFF_ENDV  48579008UL    //    400,000
#define OFF_PIDXE 48979008UL    //  2,560,000 (VERTEX ids, edge-grouped)
#define OFF_PIDXV 51539008UL    //  2,560,000 (EDGE ids, vertex-grouped)
#define OFF_CNTE  54099008UL    //     81,920 (written by scan_p2)
#define OFF_CNTV  54180928UL    //    400,000 (written by scan_p2)
#define OFF_TOT   54580928UL    //          8  } only zero region
#define ZERO_BYTES 8UL

typedef __attribute__((ext_vector_type(8))) short bf16x8;
typedef __attribute__((ext_vector_type(4))) float f32x4;

__device__ inline short f2bf(float f) {
    __hip_bfloat16 h = __float2bfloat16(f);   // RNE
    return reinterpret_cast<short&>(h);
}
__device__ inline float bf2f(short s) {
    unsigned int u = ((unsigned int)(unsigned short)s) << 16;
    union { unsigned int u; float f; } c; c.u = u;
    return c.f;
}

// ---- W prep: Wt[n][k] = bf16(W[k][n]) ----
__global__ __launch_bounds__(256) void k_wprep(const float* __restrict__ W,
                                               short* __restrict__ Wt) {
    const int idx = blockIdx.x * 256 + threadIdx.x;   // 64 * 256
    const int n = idx >> 7, k = idx & 127;
    Wt[n * CH + k] = f2bf(W[k * CH + n]);
}

// ---- gemm body: depth-2 software pipeline (load kk+1 while MFMA kk) ----
__device__ inline void gemm_body(int gb, const float* __restrict__ X,
                                 const short* __restrict__ Wt,
                                 short* __restrict__ X0h) {
    const int t = threadIdx.x;
    const int wave = t >> 6, lane = t & 63;
    const int r0 = gb * 64 + (wave >> 1) * 32;
    const int c0 = (wave & 1) * 64;
    const int lrow = lane & 15, lk8 = (lane >> 4) * 8;
    const int row0 = min(r0 + lrow, N_NODES - 1);
    const int row1 = min(r0 + 16 + lrow, N_NODES - 1);
    const float* px0 = &X[(size_t)row0 * CH + lk8];
    const float* px1 = &X[(size_t)row1 * CH + lk8];
    const short* pw0 = &Wt[(size_t)(c0 + lrow) * CH + lk8];

    f32x4 acc[2][4] = {};

    float4 xa[2][2]; bf16x8 bb[4];
    xa[0][0] = *(const float4*)(px0); xa[0][1] = *(const float4*)(px0 + 4);
    xa[1][0] = *(const float4*)(px1); xa[1][1] = *(const float4*)(px1 + 4);
#pragma unroll
    for (int n = 0; n < 4; ++n) bb[n] = *(const bf16x8*)(pw0 + n * 16 * CH);

#pragma unroll
    for (int kk = 0; kk < 4; ++kk) {
        float4 xn[2][2]; bf16x8 bn[4];
        if (kk < 3) {
            const int ks = (kk + 1) * 32;
            xn[0][0] = *(const float4*)(px0 + ks); xn[0][1] = *(const float4*)(px0 + ks + 4);
            xn[1][0] = *(const float4*)(px1 + ks); xn[1][1] = *(const float4*)(px1 + ks + 4);
#pragma unroll
            for (int n = 0; n < 4; ++n) bn[n] = *(const bf16x8*)(pw0 + n * 16 * CH + ks);
        }
        bf16x8 a[2];
#pragma unroll
        for (int m = 0; m < 2; ++m) {
            a[m][0] = f2bf(xa[m][0].x); a[m][1] = f2bf(xa[m][0].y);
            a[m][2] = f2bf(xa[m][0].z); a[m][3] = f2bf(xa[m][0].w);
            a[m][4] = f2bf(xa[m][1].x); a[m][5] = f2bf(xa[m][1].y);
            a[m][6] = f2bf(xa[m][1].z); a[m][7] = f2bf(xa[m][1].w);
        }
#pragma unroll
        for (int m = 0; m < 2; ++m)
#pragma unroll
            for (int n = 0; n < 4; ++n)
                acc[m][n] = __builtin_amdgcn_mfma_f32_16x16x32_bf16(a[m], bb[n], acc[m][n], 0, 0, 0);
        if (kk < 3) {
#pragma unroll
            for (int m = 0; m < 2; ++m) { xa[m][0] = xn[m][0]; xa[m][1] = xn[m][1]; }
#pragma unroll
            for (int n = 0; n < 4; ++n) bb[n] = bn[n];
        }
    }

    // C/D layout: col = lane&15, row = (lane>>4)*4 + reg   [m89-verified]
#pragma unroll
    for (int m = 0; m < 2; ++m) {
#pragma unroll
        for (int reg = 0; reg < 4; ++reg) {
            const int row = r0 + m * 16 + (lane >> 4) * 4 + reg;
            if (row < N_NODES) {
#pragma unroll
                for (int n = 0; n < 4; ++n)
                    X0h[(size_t)row * CH + c0 + n * 16 + (lane & 15)] = f2bf(acc[m][n][reg]);
            }
        }
    }
}

// ============ FUSED phase 1: vcount(500) | ecount(125) | gemm(1563) ============
__global__ __launch_bounds__(256) void k_phase1(const float* __restrict__ X,
                                                const short* __restrict__ Wt,
                                                short* __restrict__ X0h,
                                                const int* __restrict__ vertex,
                                                const int* __restrict__ edges,
                                                unsigned char* __restrict__ lrank_e,
                                                unsigned char* __restrict__ lrank_v,
                                                unsigned int* __restrict__ blkcnt_e,
                                                unsigned int* __restrict__ blkcnt_v) {
    __shared__ unsigned int hist[VWR];   // 25 KB
    const int bid = blockIdx.x;
    const int t = threadIdx.x;

    if (bid < NRANGE * NCHUNK) {
        const int r = bid & 3, c = bid >> 2;
        for (int i = t; i < VWR; i += 256) hist[i] = 0;
        __syncthreads();
        const int base = c * ECHUNK;
        const int vmin = r * VBIN_R;
#pragma unroll
        for (int it = 0; it < 20; ++it) {
            const int m = base + it * 256 + t;
            const int loc = vertex[m] - vmin;
            if ((unsigned)loc < (unsigned)VBIN_R) {
                const unsigned sh = (unsigned)(loc & 3) * 8u;
                unsigned old = atomicAdd(&hist[loc >> 2], 1u << sh);
                lrank_v[m] = (unsigned char)((old >> sh) & 0xffu);
            }
        }
        __syncthreads();
        unsigned int* dst = &blkcnt_v[(size_t)(r * NCHUNK + c) * VWR];
        for (int w = t; w < VWR; w += 256) dst[w] = hist[w];
        return;
    }
    if (bid < NRANGE * NCHUNK + NCHUNK) {
        const int c = bid - NRANGE * NCHUNK;
        for (int i = t; i < EW; i += 256) hist[i] = 0;
        __syncthreads();
        const int base = c * ECHUNK;
#pragma unroll
        for (int it = 0; it < 20; ++it) {
            const int m = base + it * 256 + t;
            const int e = edges[m];
            const unsigned sh = (unsigned)(e & 3) * 8u;
            unsigned old = atomicAdd(&hist[e >> 2], 1u << sh);
            lrank_e[m] = (unsigned char)((old >> sh) & 0xffu);
        }
        __syncthreads();
        unsigned int* dst = &blkcnt_e[(size_t)c * EW];
        for (int w = t; w < EW; w += 256) dst[w] = hist[w];
        return;
    }
    gemm_body(bid - (NRANGE * NCHUNK + NCHUNK), X, Wt, X0h);
}

// ---- scan p1: group partial sums (25 chunks/group); packed adds ----
__global__ __launch_bounds__(256) void k_scan_p1(const unsigned int* __restrict__ blkcnt_e,
                                                 const unsigned int* __restrict__ blkcnt_v,
                                                 unsigned int* __restrict__ gse,
                                                 unsigned int* __restrict__ gsv) {
    const int bid = blockIdx.x;
    if (bid < 100) {
        const int gid = bid * 256 + threadIdx.x;
        const int g = gid / EW, w = gid % EW;
        unsigned s = 0;
#pragma unroll 5
        for (int i = 0; i < 25; ++i) s += blkcnt_e[(size_t)(g * 25 + i) * EW + w];
        gse[g * EW + w] = s;
        return;
    }
    const int vid = (bid - 100) * 256 + threadIdx.x;
    if (vid >= 20 * VWR) return;
    const int g = vid / VWR, w = vid % VWR;
    const int r = g / 5, cg = g % 5;
    unsigned s = 0;
#pragma unroll 5
    for (int i = 0; i < 25; ++i)
        s += blkcnt_v[(size_t)(r * NCHUNK + cg * 25 + i) * VWR + w];
    gsv[g * VWR + w] = s;
}

// ---- scan p2: exclusive scan across groups + expand totals ----
__global__ __launch_bounds__(256) void k_scan_p2(unsigned int* __restrict__ gse,
                                                 unsigned int* __restrict__ gsv,
                                                 int* __restrict__ cnt_e,
                                                 int* __restrict__ cnt_v) {
    const int bid = blockIdx.x;
    if (bid < 20) {
        const int w = bid * 256 + threadIdx.x;
        unsigned run = 0;
#pragma unroll
        for (int g = 0; g < 5; ++g) {
            unsigned c = gse[g * EW + w];
            gse[g * EW + w] = run;
            run += c;
        }
        int4 o = { (int)(run & 0xffu), (int)((run >> 8) & 0xffu),
                   (int)((run >> 16) & 0xffu), (int)(run >> 24) };
        *(int4*)&cnt_e[4 * w] = o;
        return;
    }
    const int id = (bid - 20) * 256 + threadIdx.x;
    if (id >= NRANGE * VWR) return;
    const int r = id / VWR, w = id % VWR;
    unsigned run = 0;
#pragma unroll
    for (int g = r * 5; g < r * 5 + 5; ++g) {
        unsigned c = gsv[g * VWR + w];
        gsv[g * VWR + w] = run;
        run += c;
    }
    int4 o = { (int)(run & 0xffu), (int)((run >> 8) & 0xffu),
               (int)((run >> 16) & 0xffu), (int)(run >> 24) };
    *(int4*)&cnt_v[r * VBIN_R + 4 * w] = o;
}

// ---- scan p3: per-chunk exclusive prefixes ----
__global__ __launch_bounds__(256) void k_scan_p3(unsigned int* __restrict__ blkcnt_e,
                                                 unsigned int* __restrict__ blkcnt_v,
                                                 const unsigned int* __restrict__ gse,
                                                 const unsigned int* __restrict__ gsv) {
    const int bid = blockIdx.x;
    if (bid < 100) {
        const int gid = bid * 256 + threadIdx.x;
        const int g = gid / EW, w = gid % EW;
        unsigned run = gse[g * EW + w];
#pragma unroll 5
        for (int i = 0; i < 25; ++i) {
            const size_t idx = (size_t)(g * 25 + i) * EW + w;
            unsigned c = blkcnt_e[idx];
            blkcnt_e[idx] = run;
            run += c;
        }
        return;
    }
    const int vid = (bid - 100) * 256 + threadIdx.x;
    if (vid >= 20 * VWR) return;
    const int g = vid / VWR, w = vid % VWR;
    const int r = g / 5, cg = g % 5;
    unsigned run = gsv[g * VWR + w];
#pragma unroll 5
    for (int i = 0; i < 25; ++i) {
        const size_t idx = (size_t)(r * NCHUNK + cg * 25 + i) * VWR + w;
        unsigned c = blkcnt_v[idx];
        blkcnt_v[idx] = run;
        run += c;
    }
}

// ------------- offsets (both sides, role by blockIdx) -------------
__global__ __launch_bounds__(256) void k_offsets2(const int* __restrict__ cnt_e,
                                                  int* __restrict__ off_e,
                                                  int* __restrict__ end_e,
                                                  const int* __restrict__ cnt_v,
                                                  int* __restrict__ off_v,
                                                  int* __restrict__ end_v,
                                                  int* __restrict__ totals) {
    __shared__ int s[256];
    __shared__ int base;
    const int bid = blockIdx.x, t = threadIdx.x;
    const int* cnt; int* off; int* end; int* total; int n, i;
    if (bid < 79) { cnt = cnt_e; off = off_e; end = end_e; total = &totals[0]; n = N_EDGES;  i = bid * 256 + t; }
    else          { cnt = cnt_v; off = off_v; end = end_v; total = &totals[1]; n = N_NODES; i = (bid - 79) * 256 + t; }
    const int c = (i < n) ? cnt[i] : 0;
    s[t] = c;
    __syncthreads();
    for (int d = 1; d < 256; d <<= 1) {
        int x = (t >= d) ? s[t - d] : 0;
        __syncthreads();
        s[t] += x;
        __syncthreads();
    }
    if (t == 0) base = atomicAdd(total, s[255]);
    __syncthreads();
    if (i < n) {
        int o = base + s[t] - c;
        off[i] = o;
        end[i] = o + c;
    }
}

// ------- atomic-free scatter -------
__global__ __launch_bounds__(256) void k_scatter(const int* __restrict__ vertex,
                                                 const int* __restrict__ edges,
                                                 const unsigned char* __restrict__ lrank_e,
                                                 const unsigned char* __restrict__ lrank_v,
                                                 const unsigned int* __restrict__ blkcnt_e,
                                                 const unsigned int* __restrict__ blkcnt_v,
                                                 const int* __restrict__ off_e,
                                                 const int* __restrict__ off_v,
                                                 int* __restrict__ vlist_e,
                                                 int* __restrict__ elist_v) {
    const int m = blockIdx.x * 256 + threadIdx.x;
    const int e = edges[m];
    const int v = vertex[m];
    const int c = m / ECHUNK;
    const unsigned pe = blkcnt_e[(size_t)c * EW + (e >> 2)];
    const int er = (int)((pe >> ((unsigned)(e & 3) * 8u)) & 0xffu) + (int)lrank_e[m];
    const int r = v / VBIN_R, loc = v - r * VBIN_R;
    const unsigned pv = blkcnt_v[(size_t)(r * NCHUNK + c) * VWR + (loc >> 2)];
    const int vr = (int)((pv >> ((unsigned)(loc & 3) * 8u)) & 0xffu) + (int)lrank_v[m];
    vlist_e[off_e[e] + er] = v;
    elist_v[off_v[v] + vr] = e;
}

// --------- per-edge: 16 lanes x 16B gathers, two rows per iteration ---------
__global__ __launch_bounds__(256) void k_edge(const short* __restrict__ X0h,
                                              const int* __restrict__ off_e,
                                              const int* __restrict__ end_e,
                                              const int* __restrict__ vlist,
                                              const float* __restrict__ att,
                                              short* __restrict__ Xeh,
                                              float* __restrict__ alpha_le) {
    const int t = threadIdx.x;
    const int slot = t >> 5, lane = t & 31;
    const int half = lane >> 4, cl = lane & 15;    // channels [cl*8, cl*8+8)
    const int e = blockIdx.x * 8 + slot;
    const int s = off_e[e], en = end_e[e];
    const int deg = en - s;

    float va[8] = {0.f, 0.f, 0.f, 0.f, 0.f, 0.f, 0.f, 0.f};
    for (int c0 = 0; c0 < deg; c0 += 32) {
        const int cn = min(32, deg - c0);
        int vl = (lane < cn) ? vlist[s + c0 + lane] : 0;
#pragma unroll 4
        for (int j = 0; j < cn; j += 2) {
            const int jj = j + half;
            const int vj = __shfl(vl, jj, 32);
            if (jj < cn) {
                bf16x8 x = *(const bf16x8*)&X0h[(size_t)vj * CH + cl * 8];
#pragma unroll
                for (int i = 0; i < 8; ++i) va[i] += bf2f(x[i]);
            }
        }
    }
#pragma unroll
    for (int i = 0; i < 8; ++i) va[i] += __shfl_xor(va[i], 16);

    const float invd = 1.0f / fmaxf((float)deg, 1.0f);
    bf16x8 xh;
    float xe[8];
#pragma unroll
    for (int i = 0; i < 8; ++i) { xe[i] = va[i] * invd; xh[i] = f2bf(xe[i]); }
    if (half == 0) *(bf16x8*)&Xeh[(size_t)e * CH + cl * 8] = xh;

    const float4 a0 = *(const float4*)&att[cl * 8];
    const float4 a1 = *(const float4*)&att[cl * 8 + 4];
    float p = xe[0] * a0.x + xe[1] * a0.y + xe[2] * a0.z + xe[3] * a0.w
            + xe[4] * a1.x + xe[5] * a1.y + xe[6] * a1.z + xe[7] * a1.w;
    p += __shfl_xor(p, 1);
    p += __shfl_xor(p, 2);     // sum across the 4 lanes of this head group
    if (half == 0 && (cl & 3) == 0) {
        alpha_le[e * HEADS + (cl >> 2)] = (p > 0.f) ? p : 0.01f * p;
    }
}

// --------- per-vertex: 16 lanes x 16B gathers; softmax + weighted sum + residual ---------
__global__ __launch_bounds__(256) void k_vertex(const short* __restrict__ X0h,
                                                const short* __restrict__ Xeh,
                                                const float* __restrict__ alpha_le,
                                                const int* __restrict__ off_v,
                                                const int* __restrict__ end_v,
                                                const int* __restrict__ elist,
                                                float* __restrict__ out) {
    const int t = threadIdx.x;
    const int slot = t >> 5, lane = t & 31;
    const int half = lane >> 4, cl = lane & 15, h = cl >> 2;
    const int v = blockIdx.x * 8 + slot;
    const int s = off_v[v], en = end_v[v];
    const int deg = en - s;

    __shared__ int   se[8][MAXDV];
    __shared__ float sa[8][MAXDV * HEADS];

    if (deg <= MAXDV && lane < deg) {
        int e = elist[s + lane];
        se[slot][lane] = e;
        *(float4*)&sa[slot][lane << 2] = *(const float4*)&alpha_le[e * HEADS];
    }
    const bf16x8 resh = *(const bf16x8*)&X0h[(size_t)v * CH + cl * 8];
    __syncthreads();

    float va[8] = {0.f, 0.f, 0.f, 0.f, 0.f, 0.f, 0.f, 0.f};
    if (deg <= MAXDV) {
        float mx = -INFINITY;
        for (int j = 0; j < deg; ++j) mx = fmaxf(mx, sa[slot][(j << 2) + h]);
        float ssum = 0.f;
        for (int j = 0; j < deg; ++j) ssum += __expf(sa[slot][(j << 2) + h] - mx);
        const float inv = 1.0f / (ssum + 1e-8f);
#pragma unroll 2
        for (int j = 0; j < deg; j += 2) {
            const int jj = j + half;
            if (jj < deg) {
                const float w = __expf(sa[slot][(jj << 2) + h] - mx) * inv;
                bf16x8 x = *(const bf16x8*)&Xeh[(size_t)se[slot][jj] * CH + cl * 8];
#pragma unroll
                for (int i = 0; i < 8; ++i) va[i] += w * bf2f(x[i]);
            }
        }
    } else {
        // global-memory fallback (never taken for Poisson(6.4); correctness only)
        float mx = -INFINITY;
        for (int j = 0; j < deg; ++j) mx = fmaxf(mx, alpha_le[elist[s + j] * HEADS + h]);
        float ssum = 0.f;
        for (int j = 0; j < deg; ++j) ssum += __expf(alpha_le[elist[s + j] * HEADS + h] - mx);
        const float inv = 1.0f / (ssum + 1e-8f);
        for (int j = 0; j < deg; ++j) {
            if (half == 0) {
                const int e = elist[s + j];
                const float w = __expf(alpha_le[e * HEADS + h] - mx) * inv;
                bf16x8 x = *(const bf16x8*)&Xeh[(size_t)e * CH + cl * 8];
#pragma unroll
                for (int i = 0; i < 8; ++i) va[i] += w * bf2f(x[i]);
            }
        }
    }
#pragma unroll
    for (int i = 0; i < 8; ++i) va[i] += __shfl_xor(va[i], 16);

    if (half == 0) {
        float4 o0, o1;
        o0.x = va[0] + bf2f(resh[0]); o0.y = va[1] + bf2f(resh[1]);
        o0.z = va[2] + bf2f(resh[2]); o0.w = va[3] + bf2f(resh[3]);
        o1.x = va[4] + bf2f(resh[4]); o1.y = va[5] + bf2f(resh[5]);
        o1.z = va[6] + bf2f(resh[6]); o1.w = va[7] + bf2f(resh[7]);
        *(float4*)&out[(size_t)v * CH + cl * 8]     = o0;
        *(float4*)&out[(size_t)v * CH + cl * 8 + 4] = o1;
    }
}

extern "C" void kernel_launch(void* const* d_in, const int* in_sizes, int n_in,
                              void* d_out, int out_size, void* d_ws, size_t ws_size,
                              hipStream_t stream) {
    const float* X      = (const float*)d_in[0];
    const float* W      = (const float*)d_in[1];
    const float* att    = (const float*)d_in[2];
    const int*   vertex = (const int*)d_in[3];
    const int*   edges  = (const int*)d_in[4];
    float* out = (float*)d_out;

    char* ws = (char*)d_ws;
    short* X0h      = (short*)(ws + OFF_X0H);
    short* Xeh      = (short*)(ws + OFF_XEH);
    unsigned char* lrank_e = (unsigned char*)(ws + OFF_LRE);
    unsigned char* lrank_v = (unsigned char*)(ws + OFF_LRV);
    unsigned int*  blkcnt_e = (unsigned int*)(ws + OFF_BLKE);
    unsigned int*  blkcnt_v = (unsigned int*)(ws + OFF_BLKV);
    unsigned int*  gse      = (unsigned int*)(ws + OFF_GSE);
    unsigned int*  gsv      = (unsigned int*)(ws + OFF_GSV);
    short* Wt       = (short*)(ws + OFF_WT);
    float* alpha_le = (float*)(ws + OFF_ALPHA);
    int* off_e   = (int*)(ws + OFF_OFFE);
    int* end_e   = (int*)(ws + OFF_ENDE);
    int* off_v   = (int*)(ws + OFF_OFFV);
    int* end_v   = (int*)(ws + OFF_ENDV);
    int* vlist_e = (int*)(ws + OFF_PIDXE);
    int* elist_v = (int*)(ws + OFF_PIDXV);
    int* cnt_e   = (int*)(ws + OFF_CNTE);
    int* cnt_v   = (int*)(ws + OFF_CNTV);
    int* totals  = (int*)(ws + OFF_TOT);

    hipMemsetAsync(ws + OFF_TOT, 0, ZERO_BYTES, stream);

    k_wprep<<<64, 256, 0, stream>>>(W, Wt);
    k_phase1<<<NRANGE * NCHUNK + NCHUNK + NG_GEMM, 256, 0, stream>>>(
        X, Wt, X0h, vertex, edges, lrank_e, lrank_v, blkcnt_e, blkcnt_v);
    k_scan_p1<<<100 + 489, 256, 0, stream>>>(blkcnt_e, blkcnt_v, gse, gsv);
    k_scan_p2<<<20 + 98, 256, 0, stream>>>(gse, gsv, cnt_e, cnt_v);
    k_scan_p3<<<100 + 489, 256, 0, stream>>>(blkcnt_e, blkcnt_v, gse, gsv);
    k_offsets2<<<79 + 391, 256, 0, stream>>>(cnt_e, off_e, end_e, cnt_v, off_v, end_v, totals);
    k_scatter<<<N_PAIRS / 256, 256, 0, stream>>>(vertex, edges, lrank_e, lrank_v,
                                                 blkcnt_e, blkcnt_v, off_e, off_v,
                                                 vlist_e, elist_v);
    k_edge<<<N_EDGES / 8, 256, 0, stream>>>(X0h, off_e, end_e, vlist_e, att, Xeh, alpha_le);
    k_vertex<<<N_NODES / 8, 256, 0, stream>>>(X0h, Xeh, alpha_le, off_v, end_v, elist_v, out);
}